// Round 4
// baseline (144.992 us; speedup 1.0000x reference)
//
#include <hip/hip_runtime.h>
#include <math.h>

// loss = -sum_ij d1[i,j] * log(d2[i,j] + 1e-5), fp32 in, scalar fp32 out.
// Roofline: 134 MB read -> ~21 us @ 6.3 TB/s (half is L3-served after the
// harness's input restore, so the true floor may be lower).
// R1-R3 lesson: compiler clamps VGPRs (12/28/24) and drains vmcnt(0) before
// every compute stage -> only ~2-4 loads in flight -> 2.4-3.1 TB/s,
// latency-bound. Source-level pipelining is defeated by the register
// allocator. Fix: inline-asm batch of 8 global_load_dwordx4 per thread +
// partial s_waitcnt vmcnt(6/4/2/0) with "+v" operand ties so the compiler
// cannot reorder uses above their wait. Layout: 64 contiguous bytes per
// thread per input (imm offsets 0/16/32/48), wave covers a contiguous 4 KB.

#define EPS 1e-5f
#define BLOCK 256

typedef float v4f __attribute__((ext_vector_type(4)));

__global__ __launch_bounds__(BLOCK) void cep_loss_kernel(
        const float* __restrict__ d1,
        const float* __restrict__ d2,
        float* __restrict__ partials) {
    size_t t = (size_t)blockIdx.x * BLOCK + threadIdx.x;
    const char* p1 = (const char*)d1 + t * 64;   // 4 float4 per thread per input
    const char* p2 = (const char*)d2 + t * 64;

    v4f a0, b0, a1, b1, a2, b2, a3, b3;
    // 8 loads issued back-to-back: 8 KB/wave in flight, no intervening waits.
    asm volatile(
        "global_load_dwordx4 %0, %8, off\n\t"
        "global_load_dwordx4 %1, %9, off\n\t"
        "global_load_dwordx4 %2, %8, off offset:16\n\t"
        "global_load_dwordx4 %3, %9, off offset:16\n\t"
        "global_load_dwordx4 %4, %8, off offset:32\n\t"
        "global_load_dwordx4 %5, %9, off offset:32\n\t"
        "global_load_dwordx4 %6, %8, off offset:48\n\t"
        "global_load_dwordx4 %7, %9, off offset:48\n\t"
        : "=v"(a0), "=v"(b0), "=v"(a1), "=v"(b1),
          "=v"(a2), "=v"(b2), "=v"(a3), "=v"(b3)
        : "v"(p1), "v"(p2)
        : "memory");

    float acc0, acc1, acc2, acc3;

    // pair 0: wait for the 2 oldest loads only (6 still in flight)
    asm volatile("s_waitcnt vmcnt(6)" : "+v"(a0), "+v"(b0));
    acc0 = a0.x * __logf(b0.x + EPS);
    acc1 = a0.y * __logf(b0.y + EPS);
    acc2 = a0.z * __logf(b0.z + EPS);
    acc3 = a0.w * __logf(b0.w + EPS);

    asm volatile("s_waitcnt vmcnt(4)" : "+v"(a1), "+v"(b1));
    acc0 += a1.x * __logf(b1.x + EPS);
    acc1 += a1.y * __logf(b1.y + EPS);
    acc2 += a1.z * __logf(b1.z + EPS);
    acc3 += a1.w * __logf(b1.w + EPS);

    asm volatile("s_waitcnt vmcnt(2)" : "+v"(a2), "+v"(b2));
    acc0 += a2.x * __logf(b2.x + EPS);
    acc1 += a2.y * __logf(b2.y + EPS);
    acc2 += a2.z * __logf(b2.z + EPS);
    acc3 += a2.w * __logf(b2.w + EPS);

    asm volatile("s_waitcnt vmcnt(0)" : "+v"(a3), "+v"(b3));
    acc0 += a3.x * __logf(b3.x + EPS);
    acc1 += a3.y * __logf(b3.y + EPS);
    acc2 += a3.z * __logf(b3.z + EPS);
    acc3 += a3.w * __logf(b3.w + EPS);

    float acc = (acc0 + acc1) + (acc2 + acc3);

    // wave-64 shuffle reduction
    #pragma unroll
    for (int off = 32; off > 0; off >>= 1)
        acc += __shfl_down(acc, off, 64);

    __shared__ float wave_sums[BLOCK / 64];
    int lane = threadIdx.x & 63;
    int wid  = threadIdx.x >> 6;
    if (lane == 0) wave_sums[wid] = acc;
    __syncthreads();

    if (threadIdx.x == 0) {
        float s = wave_sums[0] + wave_sums[1] + wave_sums[2] + wave_sums[3];
        partials[blockIdx.x] = s;  // deterministic, no atomics
    }
}

__global__ __launch_bounds__(BLOCK) void cep_final_kernel(
        const float* __restrict__ partials, float* __restrict__ out, int nparts) {
    float acc = 0.0f;
    for (int i = threadIdx.x; i < nparts; i += BLOCK)
        acc += partials[i];

    #pragma unroll
    for (int off = 32; off > 0; off >>= 1)
        acc += __shfl_down(acc, off, 64);

    __shared__ float wave_sums[BLOCK / 64];
    int lane = threadIdx.x & 63;
    int wid  = threadIdx.x >> 6;
    if (lane == 0) wave_sums[wid] = acc;
    __syncthreads();

    if (threadIdx.x == 0) {
        float s = wave_sums[0] + wave_sums[1] + wave_sums[2] + wave_sums[3];
        out[0] = -s;
    }
}

extern "C" void kernel_launch(void* const* d_in, const int* in_sizes, int n_in,
                              void* d_out, int out_size, void* d_ws, size_t ws_size,
                              hipStream_t stream) {
    const float* d1 = (const float*)d_in[0];
    const float* d2 = (const float*)d_in[1];
    float* out = (float*)d_out;
    float* partials = (float*)d_ws;

    int n = in_sizes[0];  // 16,777,216 = 4096^2
    // Each thread consumes 16 floats per input -> grid = n / (BLOCK*16) = 4096
    const int grid = n / (BLOCK * 16);

    cep_loss_kernel<<<grid, BLOCK, 0, stream>>>(d1, d2, partials);
    cep_final_kernel<<<1, BLOCK, 0, stream>>>(partials, out, grid);
}